// Round 10
// baseline (78.940 us; speedup 1.0000x reference)
//
#include <hip/hip_runtime.h>

// Problem: B=8, N=2048, K=32, C=256, COND=512 — ALL FLOAT32 I/O, coords int32.
// Output: f32 [8,2048,256]

typedef unsigned short u16;
typedef unsigned int u32;

typedef __attribute__((ext_vector_type(8))) __bf16 bf16x8;
typedef __attribute__((ext_vector_type(4))) float f32x4;
typedef __attribute__((ext_vector_type(2))) float f32x2;
typedef __attribute__((ext_vector_type(4))) u16 u16x4;

__device__ __forceinline__ float b2f(u16 u) {
  union { u32 i; float f; } x; x.i = ((u32)u) << 16; return x.f;
}
__device__ __forceinline__ u16 f2b(float f) {
  union { float f; u32 i; } x; x.f = f;
  u32 r = (x.i + 0x7fffu + ((x.i >> 16) & 1u)) >> 16;
  return (u16)r;
}

// ---------------------------------------------------------------------------
// K0: prep.
//  blocks  0..31 : W_film repack to MFMA-B fragment order (bf16)
//  blocks 32..63 : cond GEMM partials, split over k-halves and col-halves
//                  gbp[(kh*8+b)*512 + j] = sum_{i in kh} cond[b][i]*Wc[i][j]
// ---------------------------------------------------------------------------
__global__ __launch_bounds__(256) void k_prep(const float* __restrict__ Wf,
                                              u16* __restrict__ Wp,
                                              const float* __restrict__ cond,
                                              const float* __restrict__ Wc,
                                              float* __restrict__ gbp) {
  int blk = blockIdx.x;
  int tid = threadIdx.x;
  if (blk < 32) {
    int i0 = blk * 2048 + tid;
    #pragma unroll
    for (int u = 0; u < 8; ++u) {
      int i = i0 + u * 256;
      int j  = i & 7;
      int l  = (i >> 3) & 63;
      int ks = (i >> 9) & 7;
      int ct = i >> 12;
      int k   = ks * 32 + ((l >> 4) << 3) + j;
      int col = ct * 16 + (l & 15);
      Wp[i] = f2b(Wf[k * 256 + col]);
    }
  } else {
    int idx = blk - 32;          // 0..31
    int b  = idx >> 2;           // batch 0..7
    int kh = (idx >> 1) & 1;     // k-half
    int ch = idx & 1;            // col-half
    int j  = ch * 256 + tid;
    __shared__ float cf[256];
    cf[tid] = cond[b * 512 + kh * 256 + tid];
    __syncthreads();
    float a = 0.f;
    #pragma unroll 8
    for (int i = 0; i < 256; ++i)
      a += cf[i] * Wc[(kh * 256 + i) * 512 + j];
    gbp[(kh * 8 + b) * 512 + j] = a;
  }
}

// ---------------------------------------------------------------------------
// K1: nnf = bf16( relu(LN(node_feats @ W_film + b_film) * gamma + beta) )
// 512 blocks × 256 thr (4 waves), 32 rows/block (2 row-tiles of 16).
// A staged to LDS bf16 [32][264] via flat fully-coalesced loads.
// Wave w owns col-tiles ct=w*4..w*4+3 for BOTH row-tiles (amortizes Wp reads).
// LN: intra-wave shfl over 16-lane groups, cross-wave via LDS.
// gamma/beta assembled from gbp k-partials + b_cond (+1 for gamma).
// D frag: col = ct*16+(l&15), row = rowtile + (l>>4)*4 + r
// ---------------------------------------------------------------------------
__global__ __launch_bounds__(256) void k_film(const float* __restrict__ A,
                                              const u16* __restrict__ Wp,
                                              const float* __restrict__ bfm,
                                              const float* __restrict__ gbp,
                                              const float* __restrict__ bcond,
                                              u16* __restrict__ nnf) {
  const int tid = threadIdx.x;
  const int l = tid & 63;
  const int w = tid >> 6;
  const int row0 = blockIdx.x * 32;   // 512 blocks
  const int b = row0 >> 11;

  __shared__ u16 As[32 * 264];
  __shared__ float red[4][2][4][2][4];  // [wave][rb][group][s|q][r]

  // Stage: flat coalesced, f32 -> bf16
  #pragma unroll
  for (int u = 0; u < 8; ++u) {
    int f = u * 256 + tid;            // f32x4 index
    int row = f >> 6;
    int col = (f & 63) * 4;
    f32x4 v = *(const f32x4*)(A + (size_t)(row0 + row) * 256 + col);
    u16* dst = As + row * 264 + col;
    dst[0] = f2b(v.x); dst[1] = f2b(v.y); dst[2] = f2b(v.z); dst[3] = f2b(v.w);
  }
  __syncthreads();

  f32x4 acc[2][4];
  #pragma unroll
  for (int rb = 0; rb < 2; ++rb)
    #pragma unroll
    for (int c = 0; c < 4; ++c) {
      acc[rb][c].x = 0.f; acc[rb][c].y = 0.f;
      acc[rb][c].z = 0.f; acc[rb][c].w = 0.f;
    }

  const u16* asrc = As + (l & 15) * 264 + ((l >> 4) << 3);
  const u16* wl = Wp + (size_t)l * 8;

  #pragma unroll
  for (int ks = 0; ks < 8; ++ks) {
    bf16x8 af0 = *(const bf16x8*)(asrc + ks * 32);
    bf16x8 af1 = *(const bf16x8*)(asrc + 16 * 264 + ks * 32);
    #pragma unroll
    for (int c = 0; c < 4; ++c) {
      int ct = w * 4 + c;
      bf16x8 bfr = *(const bf16x8*)(wl + ((size_t)(ct * 8 + ks)) * 512);
      acc[0][c] = __builtin_amdgcn_mfma_f32_16x16x32_bf16(af0, bfr, acc[0][c], 0, 0, 0);
      acc[1][c] = __builtin_amdgcn_mfma_f32_16x16x32_bf16(af1, bfr, acc[1][c], 0, 0, 0);
    }
  }

  const int g = l >> 4;
  #pragma unroll
  for (int rb = 0; rb < 2; ++rb) {
    float s[4] = {0.f, 0.f, 0.f, 0.f};
    float q[4] = {0.f, 0.f, 0.f, 0.f};
    #pragma unroll
    for (int c = 0; c < 4; ++c) {
      float bcol = bfm[(w * 4 + c) * 16 + (l & 15)];
      #pragma unroll
      for (int r = 0; r < 4; ++r) {
        float v = acc[rb][c][r] + bcol;
        acc[rb][c][r] = v;
        s[r] += v;
        q[r] += v * v;
      }
    }
    #pragma unroll
    for (int m = 1; m < 16; m <<= 1) {
      #pragma unroll
      for (int r = 0; r < 4; ++r) {
        s[r] += __shfl_xor(s[r], m);
        q[r] += __shfl_xor(q[r], m);
      }
    }
    if ((l & 15) == 0) {
      #pragma unroll
      for (int r = 0; r < 4; ++r) {
        red[w][rb][g][0][r] = s[r];
        red[w][rb][g][1][r] = q[r];
      }
    }
  }
  __syncthreads();

  #pragma unroll
  for (int rb = 0; rb < 2; ++rb) {
    float mu[4], rs[4];
    #pragma unroll
    for (int r = 0; r < 4; ++r) {
      float ss = red[0][rb][g][0][r] + red[1][rb][g][0][r] +
                 red[2][rb][g][0][r] + red[3][rb][g][0][r];
      float qq = red[0][rb][g][1][r] + red[1][rb][g][1][r] +
                 red[2][rb][g][1][r] + red[3][rb][g][1][r];
      mu[r] = ss * (1.0f / 256.0f);
      float var = qq * (1.0f / 256.0f) - mu[r] * mu[r];
      rs[r] = rsqrtf(var + 1e-5f);
    }
    const int rowb = row0 + rb * 16 + (g << 2);
    #pragma unroll
    for (int c = 0; c < 4; ++c) {
      int col = (w * 4 + c) * 16 + (l & 15);
      float ga = gbp[b * 512 + col] + gbp[(8 + b) * 512 + col] + bcond[col] + 1.0f;
      float be = gbp[b * 512 + 256 + col] + gbp[(8 + b) * 512 + 256 + col] + bcond[256 + col];
      #pragma unroll
      for (int r = 0; r < 4; ++r) {
        float h = (acc[rb][c][r] - mu[r]) * rs[r];
        nnf[(size_t)(rowb + r) * 256 + col] = f2b(fmaxf(h * ga + be, 0.f));
      }
    }
  }
}

// ---------------------------------------------------------------------------
// K2: out = relu(nnf + sum_k ew[k]*nnf[coords[k]])  — SELF-PHASING quarter
// loop. 1024 blocks (all co-resident at 4/CU), one per 16-row group; the
// column-quarter loop is INSIDE the block, so every resident block works on
// the same 2 MB nnf slice at the same time -> slice is L2-hot structurally,
// no dispatch-order heuristic. idx/ew staged to LDS ONCE per block (4x reuse).
// Wave w: lane group g owns row w*4+g; lane m=l&15 owns 4 cols (u16x4 = 8B;
// 16 lanes = one full 128B line; 4 lines in flight per instruction).
// ---------------------------------------------------------------------------
__global__ __launch_bounds__(256) void k_gather(const u16* __restrict__ nnf,
                                                const float* __restrict__ wts,
                                                const float* __restrict__ prm,
                                                const int* __restrict__ coords,
                                                float* __restrict__ out) {
  const int rg = blockIdx.x;          // 0..1023 (16-row group)
  const int tid = threadIdx.x;

  __shared__ int   s_idx[512];        // [16 rows][32 k]
  __shared__ float s_ew[512];

  {
    int base = rg * 512 + tid * 2;
    int2  c2 = *(const int2*)(coords + base);
    f32x2 w2 = __builtin_nontemporal_load((const f32x2*)(wts + base));
    f32x2 p2 = __builtin_nontemporal_load((const f32x2*)(prm + base));
    s_idx[tid * 2]     = c2.x;
    s_idx[tid * 2 + 1] = c2.y;
    s_ew[tid * 2]      = w2.x * p2.x;
    s_ew[tid * 2 + 1]  = w2.y * p2.y;
  }
  __syncthreads();

  const int w = tid >> 6;
  const int l = tid & 63;
  const int g = l >> 4;
  const int m = l & 15;
  const int rl = w * 4 + g;           // row-local 0..15
  const int row = rg * 16 + rl;       // 0..16383
  const int kbase = rl * 32;

  for (int q = 0; q < 4; ++q) {
    const u16* colp = nnf + q * 64 + m * 4;

    u16x4 v[32];
    #pragma unroll
    for (int k = 0; k < 32; ++k) {
      int idx = s_idx[kbase + k];     // uniform per 16-lane group
      v[k] = *(const u16x4*)(colp + ((size_t)idx << 8));
    }

    float acc[4] = {0.f, 0.f, 0.f, 0.f};
    #pragma unroll
    for (int k = 0; k < 32; ++k) {
      float wgt = s_ew[kbase + k];
      #pragma unroll
      for (int j = 0; j < 4; ++j)
        acc[j] += wgt * b2f(v[k][j]);
    }

    u16x4 sv = *(const u16x4*)(colp + ((size_t)row << 8));
    f32x4 o;
    o.x = fmaxf(b2f(sv.x) + acc[0], 0.f);
    o.y = fmaxf(b2f(sv.y) + acc[1], 0.f);
    o.z = fmaxf(b2f(sv.z) + acc[2], 0.f);
    o.w = fmaxf(b2f(sv.w) + acc[3], 0.f);
    __builtin_nontemporal_store(o, (f32x4*)(out + (size_t)row * 256 + q * 64 + m * 4));
  }
}

// ---------------------------------------------------------------------------
extern "C" void kernel_launch(void* const* d_in, const int* in_sizes, int n_in,
                              void* d_out, int out_size, void* d_ws, size_t ws_size,
                              hipStream_t stream) {
  const float* node = (const float*)d_in[0];
  const float* cond = (const float*)d_in[1];
  const float* Wc   = (const float*)d_in[2];
  const float* bc   = (const float*)d_in[3];
  const float* Wf   = (const float*)d_in[4];
  const float* bf   = (const float*)d_in[5];
  const float* wts  = (const float*)d_in[6];
  const float* prm  = (const float*)d_in[7];
  const int* coords = (const int*)d_in[8];
  float* out = (float*)d_out;

  char* ws = (char*)d_ws;
  float* gbp = (float*)ws;                        // 2*8*512 f32 = 32 KB
  u16* Wp    = (u16*)(ws + 32768);                // 128 KB
  u16* nnf   = (u16*)(ws + 32768 + 131072);       // 8 MB

  k_prep<<<dim3(64), dim3(256), 0, stream>>>(Wf, Wp, cond, Wc, gbp);
  k_film<<<dim3(512), dim3(256), 0, stream>>>(node, Wp, bf, gbp, bc, nnf);
  k_gather<<<dim3(1024), dim3(256), 0, stream>>>(nnf, wts, prm, coords, out);
}

// Round 11
// 54.234 us; speedup vs baseline: 1.4555x; 1.4555x over previous
//
#include <hip/hip_runtime.h>

// Problem: B=8, N=2048, K=32, C=256, COND=512 — ALL FLOAT32 I/O, coords int32.
// Output: f32 [8,2048,256]

typedef unsigned short u16;
typedef unsigned int u32;

typedef __attribute__((ext_vector_type(8))) __bf16 bf16x8;
typedef __attribute__((ext_vector_type(4))) __bf16 bf16x4;
typedef __attribute__((ext_vector_type(4))) float f32x4;
typedef __attribute__((ext_vector_type(2))) float f32x2;
typedef __attribute__((ext_vector_type(4))) u16 u16x4;

__device__ __forceinline__ float b2f(u16 u) {
  union { u32 i; float f; } x; x.i = ((u32)u) << 16; return x.f;
}

// ---------------------------------------------------------------------------
// K0: prep.
//  blocks  0..31 : W_film repack to MFMA-B fragment order (bf16)
//  blocks 32..63 : cond GEMM partials, split over k-halves and col-halves
//                  gbp[(kh*8+b)*512 + j] = sum_{i in kh} cond[b][i]*Wc[i][j]
// ---------------------------------------------------------------------------
__global__ __launch_bounds__(256) void k_prep(const float* __restrict__ Wf,
                                              u16* __restrict__ Wp,
                                              const float* __restrict__ cond,
                                              const float* __restrict__ Wc,
                                              float* __restrict__ gbp) {
  int blk = blockIdx.x;
  int tid = threadIdx.x;
  if (blk < 32) {
    int i0 = blk * 2048 + tid;
    #pragma unroll
    for (int u = 0; u < 8; ++u) {
      int i = i0 + u * 256;
      int j  = i & 7;
      int l  = (i >> 3) & 63;
      int ks = (i >> 9) & 7;
      int ct = i >> 12;
      int k   = ks * 32 + ((l >> 4) << 3) + j;
      int col = ct * 16 + (l & 15);
      __bf16 b = (__bf16)Wf[k * 256 + col];
      Wp[i] = *(u16*)&b;
    }
  } else {
    int idx = blk - 32;          // 0..31
    int b  = idx >> 2;           // batch 0..7
    int kh = (idx >> 1) & 1;     // k-half
    int ch = idx & 1;            // col-half
    int j  = ch * 256 + tid;
    __shared__ float cf[256];
    cf[tid] = cond[b * 512 + kh * 256 + tid];
    __syncthreads();
    float a = 0.f;
    #pragma unroll 8
    for (int i = 0; i < 256; ++i)
      a += cf[i] * Wc[(kh * 256 + i) * 512 + j];
    gbp[(kh * 8 + b) * 512 + j] = a;
  }
}

// ---------------------------------------------------------------------------
// K1: nnf = bf16( relu(LN(node_feats @ W_film + b_film) * gamma + beta) )
// 512 blocks × 256 thr (4 waves), 32 rows/block (2 row-tiles of 16).
// A staged to LDS bf16 [32][264]; conversion via NATIVE (__bf16) casts
// (compiler emits v_cvt_pk_bf16_f32 — m240) + single 8B bf16x4 LDS store.
// Wave w owns col-tiles ct=w*4..w*4+3 for BOTH row-tiles.
// LN: intra-wave shfl over 16-lane groups, cross-wave via LDS.
// D frag: col = ct*16+(l&15), row = rowtile + (l>>4)*4 + r
// ---------------------------------------------------------------------------
__global__ __launch_bounds__(256) void k_film(const float* __restrict__ A,
                                              const u16* __restrict__ Wp,
                                              const float* __restrict__ bfm,
                                              const float* __restrict__ gbp,
                                              const float* __restrict__ bcond,
                                              u16* __restrict__ nnf) {
  const int tid = threadIdx.x;
  const int l = tid & 63;
  const int w = tid >> 6;
  const int row0 = blockIdx.x * 32;   // 512 blocks
  const int b = row0 >> 11;

  __shared__ u16 As[32 * 264];
  __shared__ float red[4][2][4][2][4];  // [wave][rb][group][s|q][r]

  // Stage: flat coalesced, f32 -> bf16 (cvt_pk), one 8B store per thread-iter
  #pragma unroll
  for (int u = 0; u < 8; ++u) {
    int f = u * 256 + tid;            // f32x4 index
    int row = f >> 6;
    int col = (f & 63) * 4;
    f32x4 v = *(const f32x4*)(A + (size_t)(row0 + row) * 256 + col);
    bf16x4 pk;
    pk[0] = (__bf16)v.x; pk[1] = (__bf16)v.y;
    pk[2] = (__bf16)v.z; pk[3] = (__bf16)v.w;
    *(bf16x4*)(As + row * 264 + col) = pk;
  }
  __syncthreads();

  f32x4 acc[2][4];
  #pragma unroll
  for (int rb = 0; rb < 2; ++rb)
    #pragma unroll
    for (int c = 0; c < 4; ++c) {
      acc[rb][c].x = 0.f; acc[rb][c].y = 0.f;
      acc[rb][c].z = 0.f; acc[rb][c].w = 0.f;
    }

  const u16* asrc = As + (l & 15) * 264 + ((l >> 4) << 3);
  const u16* wl = Wp + (size_t)l * 8;

  #pragma unroll
  for (int ks = 0; ks < 8; ++ks) {
    bf16x8 af0 = *(const bf16x8*)(asrc + ks * 32);
    bf16x8 af1 = *(const bf16x8*)(asrc + 16 * 264 + ks * 32);
    #pragma unroll
    for (int c = 0; c < 4; ++c) {
      int ct = w * 4 + c;
      bf16x8 bfr = *(const bf16x8*)(wl + ((size_t)(ct * 8 + ks)) * 512);
      acc[0][c] = __builtin_amdgcn_mfma_f32_16x16x32_bf16(af0, bfr, acc[0][c], 0, 0, 0);
      acc[1][c] = __builtin_amdgcn_mfma_f32_16x16x32_bf16(af1, bfr, acc[1][c], 0, 0, 0);
    }
  }

  const int g = l >> 4;
  #pragma unroll
  for (int rb = 0; rb < 2; ++rb) {
    float s[4] = {0.f, 0.f, 0.f, 0.f};
    float q[4] = {0.f, 0.f, 0.f, 0.f};
    #pragma unroll
    for (int c = 0; c < 4; ++c) {
      float bcol = bfm[(w * 4 + c) * 16 + (l & 15)];
      #pragma unroll
      for (int r = 0; r < 4; ++r) {
        float v = acc[rb][c][r] + bcol;
        acc[rb][c][r] = v;
        s[r] += v;
        q[r] += v * v;
      }
    }
    #pragma unroll
    for (int m = 1; m < 16; m <<= 1) {
      #pragma unroll
      for (int r = 0; r < 4; ++r) {
        s[r] += __shfl_xor(s[r], m);
        q[r] += __shfl_xor(q[r], m);
      }
    }
    if ((l & 15) == 0) {
      #pragma unroll
      for (int r = 0; r < 4; ++r) {
        red[w][rb][g][0][r] = s[r];
        red[w][rb][g][1][r] = q[r];
      }
    }
  }
  __syncthreads();

  // hoisted gamma/beta per col (same for both row-tiles)
  float ga[4], be[4];
  #pragma unroll
  for (int c = 0; c < 4; ++c) {
    int col = (w * 4 + c) * 16 + (l & 15);
    ga[c] = gbp[b * 512 + col] + gbp[(8 + b) * 512 + col] + bcond[col] + 1.0f;
    be[c] = gbp[b * 512 + 256 + col] + gbp[(8 + b) * 512 + 256 + col] + bcond[256 + col];
  }

  #pragma unroll
  for (int rb = 0; rb < 2; ++rb) {
    float mu[4], rs[4];
    #pragma unroll
    for (int r = 0; r < 4; ++r) {
      float ss = red[0][rb][g][0][r] + red[1][rb][g][0][r] +
                 red[2][rb][g][0][r] + red[3][rb][g][0][r];
      float qq = red[0][rb][g][1][r] + red[1][rb][g][1][r] +
                 red[2][rb][g][1][r] + red[3][rb][g][1][r];
      mu[r] = ss * (1.0f / 256.0f);
      float var = qq * (1.0f / 256.0f) - mu[r] * mu[r];
      rs[r] = rsqrtf(var + 1e-5f);
    }
    const int rowb = row0 + rb * 16 + (g << 2);
    #pragma unroll
    for (int c = 0; c < 4; ++c) {
      int col = (w * 4 + c) * 16 + (l & 15);
      #pragma unroll
      for (int r = 0; r < 4; ++r) {
        float h = (acc[rb][c][r] - mu[r]) * rs[r];
        float o = fmaxf(h * ga[c] + be[c], 0.f);
        ((__bf16*)nnf)[(size_t)(rowb + r) * 256 + col] = (__bf16)o;
      }
    }
  }
}

// ---------------------------------------------------------------------------
// K2: out = relu(nnf + sum_k ew[k]*nnf[coords[k]])  — column-quarter sliced,
// QUAD-ROW waves + LDS idx/ew broadcast (r9 structure — best known).
// Block = 4 waves = 16 rows × one quarter. coords/ew staged to LDS (4 KB).
// Wave w: lane group g=l>>4 owns row w*4+g; lane m=l&15 owns 4 cols (u16x4,
// 8B; 16 lanes = one full 128B line). One gather instruction = 4 DIFFERENT
// lines in flight. idx/ew via per-group-uniform ds_read. All 32 gathers
// prefetched to registers. Quarter phased via dispatch order.
// ---------------------------------------------------------------------------
__global__ __launch_bounds__(256) void k_gather(const u16* __restrict__ nnf,
                                                const float* __restrict__ wts,
                                                const float* __restrict__ prm,
                                                const int* __restrict__ coords,
                                                float* __restrict__ out) {
  const int q  = blockIdx.x >> 10;    // 0..3
  const int rg = blockIdx.x & 1023;   // 16-row group
  const int tid = threadIdx.x;

  __shared__ int   s_idx[512];        // [16 rows][32 k]
  __shared__ float s_ew[512];

  {
    int base = rg * 512 + tid * 2;
    int2  c2 = *(const int2*)(coords + base);
    f32x2 w2 = __builtin_nontemporal_load((const f32x2*)(wts + base));
    f32x2 p2 = __builtin_nontemporal_load((const f32x2*)(prm + base));
    s_idx[tid * 2]     = c2.x;
    s_idx[tid * 2 + 1] = c2.y;
    s_ew[tid * 2]      = w2.x * p2.x;
    s_ew[tid * 2 + 1]  = w2.y * p2.y;
  }
  __syncthreads();

  const int w = tid >> 6;
  const int l = tid & 63;
  const int g = l >> 4;
  const int m = l & 15;
  const int rl = w * 4 + g;           // row-local 0..15
  const int row = rg * 16 + rl;       // 0..16383
  const int kbase = rl * 32;
  const u16* colp = nnf + q * 64 + m * 4;

  u16x4 v[32];
  #pragma unroll
  for (int k = 0; k < 32; ++k) {
    int idx = s_idx[kbase + k];       // uniform per 16-lane group
    v[k] = *(const u16x4*)(colp + ((size_t)idx << 8));
  }

  float acc[4] = {0.f, 0.f, 0.f, 0.f};
  #pragma unroll
  for (int k = 0; k < 32; ++k) {
    float wgt = s_ew[kbase + k];
    #pragma unroll
    for (int j = 0; j < 4; ++j)
      acc[j] += wgt * b2f(v[k][j]);
  }

  u16x4 sv = *(const u16x4*)(colp + ((size_t)row << 8));
  f32x4 o;
  o.x = fmaxf(b2f(sv.x) + acc[0], 0.f);
  o.y = fmaxf(b2f(sv.y) + acc[1], 0.f);
  o.z = fmaxf(b2f(sv.z) + acc[2], 0.f);
  o.w = fmaxf(b2f(sv.w) + acc[3], 0.f);
  __builtin_nontemporal_store(o, (f32x4*)(out + (size_t)row * 256 + q * 64 + m * 4));
}

// ---------------------------------------------------------------------------
extern "C" void kernel_launch(void* const* d_in, const int* in_sizes, int n_in,
                              void* d_out, int out_size, void* d_ws, size_t ws_size,
                              hipStream_t stream) {
  const float* node = (const float*)d_in[0];
  const float* cond = (const float*)d_in[1];
  const float* Wc   = (const float*)d_in[2];
  const float* bc   = (const float*)d_in[3];
  const float* Wf   = (const float*)d_in[4];
  const float* bf   = (const float*)d_in[5];
  const float* wts  = (const float*)d_in[6];
  const float* prm  = (const float*)d_in[7];
  const int* coords = (const int*)d_in[8];
  float* out = (float*)d_out;

  char* ws = (char*)d_ws;
  float* gbp = (float*)ws;                        // 2*8*512 f32 = 32 KB
  u16* Wp    = (u16*)(ws + 32768);                // 128 KB
  u16* nnf   = (u16*)(ws + 32768 + 131072);       // 8 MB

  k_prep<<<dim3(64), dim3(256), 0, stream>>>(Wf, Wp, cond, Wc, gbp);
  k_film<<<dim3(512), dim3(256), 0, stream>>>(node, Wp, bf, gbp, bc, nnf);
  k_gather<<<dim3(4096), dim3(256), 0, stream>>>(nnf, wts, prm, coords, out);
}